// Round 2
// baseline (148.984 us; speedup 1.0000x reference)
//
#include <hip/hip_runtime.h>
#include <hip/hip_fp16.h>

// Problem constants (fixed by the reference setup)
constexpr int N = 4096;
constexpr int D = 512;
constexpr int NT = 32;                   // 4096 / 128 tile-rows
constexpr int NBLK = NT * (NT + 1) / 2;  // 528 upper-triangle tiles
constexpr int NWM = NBLK * 8;            // 4224 per-wave 64x32 region maxes
constexpr float SENT = -1e30f;           // sentinel (invalid sites / empty slots)
constexpr unsigned TCV = 8386560u;       // N*(N-1)/2 valid strict-upper pairs

// Candidate collection: every loss >= T0 goes to a global buffer in K1.
// sims ~ N(0, 1/512) => P(loss >= 0.63) ~ 1.6e-3 => ~14K values expected.
// CAP = 32768 gives ~+160 sigma margin; exactness does NOT depend on this:
// finalize falls back to threshold-recompute (path B) if count < 10 or > CAP.
constexpr float T0 = 0.63f;
constexpr unsigned CAP = 32768;
constexpr int MFIN = 64;  // CAP / 512 = per-thread regs in finalize path A

typedef _Float16 f16x8 __attribute__((ext_vector_type(8)));
typedef float f32x4 __attribute__((ext_vector_type(4)));

// async 16B/lane global->LDS (wave-uniform LDS base + lane*16)
__device__ __forceinline__ void load_lds16(const _Float16* g, _Float16* l) {
  __builtin_amdgcn_global_load_lds(
      (const __attribute__((address_space(1))) void*)g,
      (__attribute__((address_space(3))) void*)l, 16, 0, 0);
}

// Exact wave top-10 by repeated selection over per-lane register candidates.
// out[r] ends up wave-uniform. Duplicates preserved (leader pops ONE copy).
// NOTE: mutates vals[] on leader lanes.
template <int M>
__device__ __forceinline__ void wave_sel10(float (&vals)[M], float (&out)[10]) {
  int lane = threadIdx.x & 63;
  float lm = vals[0];
#pragma unroll
  for (int k = 1; k < M; k++) lm = fmaxf(lm, vals[k]);
#pragma unroll
  for (int r = 0; r < 10; r++) {
    float wmx = lm;
#pragma unroll
    for (int ofs = 1; ofs < 64; ofs <<= 1)
      wmx = fmaxf(wmx, __shfl_xor(wmx, ofs));
    out[r] = wmx;
    unsigned long long b = __ballot(lm == wmx);
    int leader = __ffsll(b) - 1;
    if (lane == leader) {
      bool found = false;
#pragma unroll
      for (int k = 0; k < M; k++) {
        bool hit = !found && (vals[k] == wmx);
        vals[k] = hit ? SENT : vals[k];
        found = found || hit;
      }
      lm = vals[0];
#pragma unroll
      for (int k = 1; k < M; k++) lm = fmaxf(lm, vals[k]);
    }
  }
}

// ws layout (bytes; ws is 256 MiB per the harness fill counters):
//   [0, 23232)   stats slots: f32 sumv[528]; f32 sump[528]; u32 cntpack[528];
//                f32 wmax[528*8]
//   23232        u32 ncand (zeroed by prep each launch)
//   126976       f16 Xh[N*D]            (4 MiB)
//   8388608      f32 cand[CAP]          (128 KiB)
constexpr int NCAND_OFF = 23232;
constexpr int XH_OFF = 126976;
constexpr size_t CAND_OFF = 8388608;

// ---------------- K0: fp32 -> f16 convert (+ zero ncand) ----------------
__global__ void prep_kernel(const float4* __restrict__ X4,
                            ushort4* __restrict__ Xh4,
                            unsigned* __restrict__ ncand) {
  int gid = blockIdx.x * 256 + threadIdx.x;  // grid exactly N*D/4 threads
  if (gid == 0) *ncand = 0u;
  float4 v = X4[gid];
  ushort4 o;
  o.x = __half_as_ushort(__float2half_rn(v.x));
  o.y = __half_as_ushort(__float2half_rn(v.y));
  o.z = __half_as_ushort(__float2half_rn(v.z));
  o.w = __half_as_ushort(__float2half_rn(v.w));
  Xh4[gid] = o;
}

// ---------------- K1: 128x128-tile X*X^T, dbuf, stats+max+collect ----------
// 528 blocks x 512 threads (8 waves, 2M x 4N wave grid, 64x32 per wave).
// LDS 64 KB dbuf -> 2 blocks/CU. One barrier per K-step (verified round 1).
__global__ __launch_bounds__(512, 4) void gemm_stats_kernel(
    const _Float16* __restrict__ Xh, const int* __restrict__ tgt,
    float* __restrict__ slots, float* __restrict__ cand,
    unsigned* __restrict__ ncand) {
  __shared__ _Float16 As[2][128 * 64];  // 2 x 16 KB
  __shared__ _Float16 Bs[2][128 * 64];  // 2 x 16 KB
  __shared__ int tA[128], tB[128];
  __shared__ float redf[2][8];
  __shared__ unsigned redu[8];

  int tid = threadIdx.x;

  // decode upper-triangle tile (br <= bc)
  int id = blockIdx.x, br = 0;
  while (id >= (NT - br)) { id -= (NT - br); br++; }
  int bc = br + id;

  if (tid < 128) tA[tid] = tgt[br * 128 + tid];
  else if (tid < 256) tB[tid - 128] = tgt[bc * 128 + (tid - 128)];

  int lane = tid & 63, wave = tid >> 6;
  int wm2 = (wave >> 2) << 6;  // 0 or 64: wave row-half
  int wn2 = (wave & 3) << 5;   // 0,32,64,96: wave col-quarter
  int lrow = lane & 15;
  int q4 = lane >> 4;
  int x7 = lrow & 7;
  int quad4 = q4 * 4;

  // staging: issue i (0..1) covers chunks C = i*512 + tid (1024 16B chunks
  // per matrix); row = C>>3, pos p = C&7 holds global chunk p^(row&7).
  int srow[2], scol[2], sdst[2];
#pragma unroll
  for (int i = 0; i < 2; i++) {
    int C = i * 512 + tid;
    int row = C >> 3, p = C & 7;
    srow[i] = row;
    scol[i] = (p ^ (row & 7)) * 8;
    sdst[i] = (i * 8 + wave) * 512;  // wave-uniform elem base (+lane*8 by HW)
  }
  const _Float16* Arow = Xh + (size_t)(br * 128) * D;
  const _Float16* Brow = Xh + (size_t)(bc * 128) * D;

  // prologue: stage k0=0 into buffer 0
#pragma unroll
  for (int i = 0; i < 2; i++) {
    load_lds16(Arow + srow[i] * D + scol[i], &As[0][sdst[i]]);
    load_lds16(Brow + srow[i] * D + scol[i], &Bs[0][sdst[i]]);
  }

  f32x4 acc[4][2] = {};
#pragma unroll
  for (int t = 0; t < 8; t++) {
    int cur = t & 1;
    __syncthreads();  // drains vmcnt: buf[cur] visible; buf[cur^1] free
    if (t < 7) {
      int k0 = (t + 1) * 64;
#pragma unroll
      for (int i = 0; i < 2; i++) {
        load_lds16(Arow + srow[i] * D + k0 + scol[i], &As[cur ^ 1][sdst[i]]);
        load_lds16(Brow + srow[i] * D + k0 + scol[i], &Bs[cur ^ 1][sdst[i]]);
      }
    }
#pragma unroll
    for (int ks = 0; ks < 64; ks += 32) {
      int c0 = ks >> 3;
      f16x8 af[4], bf[2];
#pragma unroll
      for (int mi = 0; mi < 4; mi++)
        af[mi] = *(const f16x8*)&As[cur][(wm2 + mi * 16 + lrow) * 64 +
                                         ((c0 + q4) ^ x7) * 8];
#pragma unroll
      for (int ni = 0; ni < 2; ni++)
        bf[ni] = *(const f16x8*)&Bs[cur][(wn2 + ni * 16 + lrow) * 64 +
                                         ((c0 + q4) ^ x7) * 8];
#pragma unroll
      for (int mi = 0; mi < 4; mi++)
#pragma unroll
        for (int ni = 0; ni < 2; ni++)
          acc[mi][ni] = __builtin_amdgcn_mfma_f32_16x16x32_f16(
              af[mi], bf[ni], acc[mi][ni], 0, 0, 0);
    }
  }

  // ---- epilogue: stats + per-wave region max + threshold collection ----
  int tj[2];
#pragma unroll
  for (int ni = 0; ni < 2; ni++) tj[ni] = tB[wn2 + ni * 16 + lrow];

  float lsv = 0.f, lsp = 0.f, tmax = SENT;
  unsigned cz = 0;  // cntp | zeros<<16 (block totals <= 16384 each)
  unsigned cc = 0;  // per-thread count of losses >= T0
  int ib = br * 128 + wm2 + quad4;
  int jb = bc * 128 + wn2 + lrow;
#pragma unroll
  for (int mi = 0; mi < 4; mi++) {
#pragma unroll
    for (int r = 0; r < 4; r++) {
      int trow = tA[wm2 + mi * 16 + quad4 + r];
      int i = ib + mi * 16 + r;
#pragma unroll
      for (int ni = 0; ni < 2; ni++) {
        float s = acc[mi][ni][r];
        int j = jb + ni * 16;
        bool valid = j > i;  // strict upper triangle; doubled at the end
        bool pos = valid && (trow == tj[ni]);
        float loss = fmaxf(0.5f + (pos ? -s : s), 0.0f);
        if (valid) {
          lsv += s;
          if (loss == 0.0f) cz += 0x10000u;
          if (loss >= T0) cc++;
        }
        if (pos) { lsp += s; cz += 1u; }
        tmax = fmaxf(tmax, valid ? loss : SENT);
      }
    }
  }
  float lmax = tmax;
#pragma unroll
  for (int o = 32; o > 0; o >>= 1) {
    lsv += __shfl_down(lsv, o);
    lsp += __shfl_down(lsp, o);
    cz += __shfl_down(cz, o);
    lmax = fmaxf(lmax, __shfl_down(lmax, o));
  }
  if (lane == 0) {
    redf[0][wave] = lsv; redf[1][wave] = lsp; redu[wave] = cz;
    slots[3 * NBLK + blockIdx.x * 8 + wave] = lmax;  // region max (fallback)
  }

  // threshold collection: wave prefix-scan + one atomic + scattered stores
  if (__ballot(cc != 0)) {
    unsigned inc = cc;
#pragma unroll
    for (int o = 1; o < 64; o <<= 1) {
      unsigned t = __shfl_up(inc, o);
      if (lane >= o) inc += t;
    }
    unsigned base = 0;
    if (lane == 63) base = atomicAdd(ncand, inc);  // inc@63 = wave total
    base = __shfl(base, 63);
    unsigned p = base + inc - cc;  // exclusive prefix
    if (cc) {
#pragma unroll
      for (int mi = 0; mi < 4; mi++) {
#pragma unroll
        for (int r = 0; r < 4; r++) {
          int trow = tA[wm2 + mi * 16 + quad4 + r];
          int i = ib + mi * 16 + r;
#pragma unroll
          for (int ni = 0; ni < 2; ni++) {
            float s = acc[mi][ni][r];
            int j = jb + ni * 16;
            bool valid = j > i;
            bool pos = valid && (trow == tj[ni]);
            float loss = fmaxf(0.5f + (pos ? -s : s), 0.0f);
            if (valid && loss >= T0) {
              if (p < CAP) cand[p] = loss;
              p++;
            }
          }
        }
      }
    }
  }
  __syncthreads();
  if (tid == 0) {
    float a = 0.f, b = 0.f;
    unsigned c = 0;
#pragma unroll
    for (int w = 0; w < 8; w++) { a += redf[0][w]; b += redf[1][w]; c += redu[w]; }
    slots[blockIdx.x] = a;
    slots[NBLK + blockIdx.x] = b;
    ((unsigned*)slots)[2 * NBLK + blockIdx.x] = c;
  }
}

// ---------------- K2: single-block finalize ----------------
// Path A (always on this data): top-10 over the collected cand buffer.
// Path B (fallback, exact): T = 10th-largest region max; recompute candidate
// regions bit-identically and collect values >= T (verified round 1).
__device__ __forceinline__ void load_frags(const _Float16* __restrict__ Xh,
                                           int r0, int c0, int kk, int lrow,
                                           int q4, f16x8 (&af)[4],
                                           f16x8 (&bf)[2]) {
#pragma unroll
  for (int mi = 0; mi < 4; mi++)
    af[mi] = *(const f16x8*)&Xh[(size_t)(r0 + mi * 16 + lrow) * D + kk + q4 * 8];
#pragma unroll
  for (int ni = 0; ni < 2; ni++)
    bf[ni] = *(const f16x8*)&Xh[(size_t)(c0 + ni * 16 + lrow) * D + kk + q4 * 8];
}

__device__ __forceinline__ void mfma8(f32x4 (&a4)[4][2], f16x8 (&af)[4],
                                      f16x8 (&bf)[2]) {
#pragma unroll
  for (int mi = 0; mi < 4; mi++)
#pragma unroll
    for (int ni = 0; ni < 2; ni++)
      a4[mi][ni] = __builtin_amdgcn_mfma_f32_16x16x32_f16(af[mi], bf[ni],
                                                          a4[mi][ni], 0, 0, 0);
}

__global__ __launch_bounds__(512) void finalize_kernel(
    const _Float16* __restrict__ Xh, const int* __restrict__ tgt,
    const float* __restrict__ slots, const float* __restrict__ cand,
    const unsigned* __restrict__ ncand, float* __restrict__ out) {
  const float* sumv = slots;
  const float* sump = slots + NBLK;
  const unsigned* cnts = (const unsigned*)(slots + 2 * NBLK);
  const float* wmax = slots + 3 * NBLK;

  __shared__ float svals[2048];
  __shared__ int scand[1024];
  __shared__ float wml[80];
  __shared__ float redf[2][8];
  __shared__ unsigned redu2[2][8];
  __shared__ unsigned snc, snv;
  __shared__ float sT;

  int tid = threadIdx.x, lane = tid & 63, wave = tid >> 6;
  if (tid == 0) { snc = 0u; snv = 0u; }

  // stats partials over 528 block rows
  float sv = 0.f, sp = 0.f;
  unsigned cp = 0, zz = 0;
#pragma unroll
  for (int k = 0; k < 2; k++) {
    int r = tid + k * 512;
    if (r < NBLK) {
      sv += sumv[r]; sp += sump[r];
      unsigned c = cnts[r];
      cp += c & 0xffffu; zz += c >> 16;
    }
  }
#pragma unroll
  for (int o = 32; o > 0; o >>= 1) {
    sv += __shfl_down(sv, o); sp += __shfl_down(sp, o);
    cp += __shfl_down(cp, o); zz += __shfl_down(zz, o);
  }
  if (lane == 0) {
    redf[0][wave] = sv; redf[1][wave] = sp;
    redu2[0][wave] = cp; redu2[1][wave] = zz;
  }

  unsigned nv = *ncand;
  bool pathA = (nv >= 10u && nv <= CAP);  // block-uniform branch

  if (pathA) {
    // top-10 over collected values: 512 threads x up to MFIN regs
    float v[MFIN];
#pragma unroll
    for (int k = 0; k < MFIN; k++) {
      int g = tid + k * 512;
      v[k] = (g < (int)nv) ? cand[g] : SENT;
    }
    float wl[10];
    wave_sel10<MFIN>(v, wl);
    if (lane == 0) {
#pragma unroll
      for (int r = 0; r < 10; r++) wml[wave * 10 + r] = wl[r];
    }
  } else {
    // ---- fallback: threshold from region maxes + bit-identical recompute
    float mv[9], keep[9];
#pragma unroll
    for (int k = 0; k < 9; k++) {
      int g = tid + k * 512;
      mv[k] = (g < NWM) ? wmax[g] : SENT;
      keep[k] = mv[k];
    }
    float wl[10];
    wave_sel10<9>(mv, wl);
    if (lane == 0) {
#pragma unroll
      for (int r = 0; r < 10; r++) wml[wave * 10 + r] = wl[r];
    }
    __syncthreads();
    if (wave == 0) {
      float m2[2];
      m2[0] = wml[lane];
      m2[1] = (lane + 64 < 80) ? wml[lane + 64] : SENT;
      float t10[10];
      wave_sel10<2>(m2, t10);
      if (lane == 0) sT = t10[9];
    }
    __syncthreads();
    float T = sT;

    // candidate regions (max >= T)
#pragma unroll
    for (int k = 0; k < 9; k++) {
      int g = tid + k * 512;
      if (g < NWM && keep[k] >= T) {
        unsigned p = atomicAdd(&snc, 1u);
        if (p < 1024u) scand[p] = g;
      }
    }
    __syncthreads();

    int nu = (int)snc;
    if (nu > 1024) nu = 1024;
    int lrow = lane & 15, q4 = lane >> 4, quad4 = q4 * 4;
    for (int u = wave; u < nu; u += 8) {
      int g = scand[u];
      int cb = g >> 3, wr = g & 7;
      int idd = cb, br = 0;
      while (idd >= (NT - br)) { idd -= (NT - br); br++; }
      int bc = br + idd;
      int r0 = br * 128 + ((wr >> 2) << 6);
      int c0 = bc * 128 + ((wr & 3) << 5);

      f32x4 a4[4][2] = {};
      f16x8 af0[4], bf0[2], af1[4], bf1[2];
      load_frags(Xh, r0, c0, 0, lrow, q4, af0, bf0);
#pragma unroll
      for (int kk = 0; kk < D; kk += 64) {  // K-order matches K1's chain
        load_frags(Xh, r0, c0, kk + 32, lrow, q4, af1, bf1);
        mfma8(a4, af0, bf0);
        if (kk + 64 < D) load_frags(Xh, r0, c0, kk + 64, lrow, q4, af0, bf0);
        mfma8(a4, af1, bf1);
      }
      int tj[2];
#pragma unroll
      for (int ni = 0; ni < 2; ni++) tj[ni] = tgt[c0 + ni * 16 + lrow];
#pragma unroll
      for (int mi = 0; mi < 4; mi++) {
#pragma unroll
        for (int r = 0; r < 4; r++) {
          int i = r0 + mi * 16 + quad4 + r;
          int trow = tgt[i];
#pragma unroll
          for (int ni = 0; ni < 2; ni++) {
            int j = c0 + ni * 16 + lrow;
            float s = a4[mi][ni][r];
            bool valid = j > i;
            bool pos = valid && (trow == tj[ni]);
            float loss = fmaxf(0.5f + (pos ? -s : s), 0.0f);
            if (valid && loss >= T) {
              unsigned p = atomicAdd(&snv, 1u);
              if (p < 2048u) svals[p] = loss;
            }
          }
        }
      }
    }
    __syncthreads();

    int nvv = (int)snv;
    if (nvv > 2048) nvv = 2048;
    float v4[4];
#pragma unroll
    for (int k = 0; k < 4; k++) {
      int g = tid + k * 512;
      v4[k] = (g < nvv) ? svals[g] : SENT;
    }
    float wl2[10];
    wave_sel10<4>(v4, wl2);
    if (lane == 0) {
#pragma unroll
      for (int r = 0; r < 10; r++) wml[wave * 10 + r] = wl2[r];
    }
  }

  __syncthreads();  // wml + redf/redu2 visible

  if (wave == 0) {
    float m2[2];
    m2[0] = wml[lane];
    m2[1] = (lane + 64 < 80) ? wml[lane + 64] : SENT;
    float f10[10];
    wave_sel10<2>(m2, f10);
    if (lane == 0) {
      float topsum = 0.f;
#pragma unroll
      for (int r = 0; r < 10; r++) topsum += f10[r];
      float a = 0.f, b = 0.f;
      unsigned c2 = 0, z2 = 0;
#pragma unroll
      for (int w = 0; w < 8; w++) {
        a += redf[0][w]; b += redf[1][w];
        c2 += redu2[0][w]; z2 += redu2[1][w];
      }
      // full-matrix multiset = upper-triangle doubled: top-20 mean == top-10
      // mean; counts double in numerator and denominator (cancel in means)
      out[0] = topsum * 0.1f;
      out[1] = (float)(2u * z2);
      out[2] = b / (float)c2;
      out[3] = (a - b) / (float)(TCV - c2);
    }
  }
}

extern "C" void kernel_launch(void* const* d_in, const int* in_sizes, int n_in,
                              void* d_out, int out_size, void* d_ws,
                              size_t ws_size, hipStream_t stream) {
  const float* X = (const float*)d_in[0];
  const int* tgt = (const int*)d_in[1];
  float* out = (float*)d_out;
  char* ws = (char*)d_ws;

  float* slots = (float*)ws;
  unsigned* ncand = (unsigned*)(ws + NCAND_OFF);
  _Float16* Xh = (_Float16*)(ws + XH_OFF);
  float* cand = (float*)(ws + CAND_OFF);

  prep_kernel<<<(N * D / 4) / 256, 256, 0, stream>>>((const float4*)X,
                                                     (ushort4*)Xh, ncand);
  gemm_stats_kernel<<<NBLK, 512, 0, stream>>>(Xh, tgt, slots, cand, ncand);
  finalize_kernel<<<1, 512, 0, stream>>>(Xh, tgt, slots, cand, ncand, out);
}

// Round 3
// 114.564 us; speedup vs baseline: 1.3004x; 1.3004x over previous
//
#include <hip/hip_runtime.h>
#include <hip/hip_fp16.h>

// Problem constants (fixed by the reference setup)
constexpr int N = 4096;
constexpr int D = 512;
constexpr int NT = 32;                   // 4096 / 128 tile-rows
constexpr int NBLK = NT * (NT + 1) / 2;  // 528 upper-triangle tiles
constexpr int NSEG = 33;                 // finalize segments
constexpr int SEGSZ = 16;                // 528 / 33 blocks per segment
constexpr float SENT = -1e30f;           // sentinel (invalid sites / empty slots)
constexpr unsigned TCV = 8386560u;       // N*(N-1)/2 valid strict-upper pairs

typedef _Float16 f16x8 __attribute__((ext_vector_type(8)));
typedef float f32x4 __attribute__((ext_vector_type(4)));

// async 16B/lane global->LDS (wave-uniform LDS base + lane*16)
__device__ __forceinline__ void load_lds16(const _Float16* g, _Float16* l) {
  __builtin_amdgcn_global_load_lds(
      (const __attribute__((address_space(1))) void*)g,
      (__attribute__((address_space(3))) void*)l, 16, 0, 0);
}

// Exact wave top-10 by repeated selection over per-lane register candidates.
// out[r] ends up wave-uniform. Duplicates preserved (leader pops ONE copy).
// NOTE: mutates vals[] on leader lanes.
template <int M>
__device__ __forceinline__ void wave_sel10(float (&vals)[M], float (&out)[10]) {
  int lane = threadIdx.x & 63;
  float lm = vals[0];
#pragma unroll
  for (int k = 1; k < M; k++) lm = fmaxf(lm, vals[k]);
#pragma unroll
  for (int r = 0; r < 10; r++) {
    float wmx = lm;
#pragma unroll
    for (int ofs = 1; ofs < 64; ofs <<= 1)
      wmx = fmaxf(wmx, __shfl_xor(wmx, ofs));
    out[r] = wmx;
    unsigned long long b = __ballot(lm == wmx);
    int leader = __ffsll(b) - 1;
    if (lane == leader) {
      bool found = false;
#pragma unroll
      for (int k = 0; k < M; k++) {
        bool hit = !found && (vals[k] == wmx);
        vals[k] = hit ? SENT : vals[k];
        found = found || hit;
      }
      lm = vals[0];
#pragma unroll
      for (int k = 1; k < M; k++) lm = fmaxf(lm, vals[k]);
    }
  }
}

// ws layout (float indices unless noted):
//   [0, 528)       f32 blk_sumv
//   [528, 1056)    f32 blk_sump
//   [1056, 1584)   u32 cntpack  (cntp | zeros<<16; per-block totals <= 16384)
//   [1584, 6864)   f32 top10g[528*10]
//   6864           u32 done2 (zeroed by prep)
//   [6880, 7342)   segL2: f32 ssumv[33]; f32 ssump[33]; u32 scv[33];
//                  u32 szz[33]; f32 st10[330]
//   byte 32768:    f16 Xh[N*D]
constexpr int TOP10G_IDX = 1584;
constexpr int DONE2_IDX = 6864;
constexpr int SEGL2_IDX = 6880;
constexpr int XH_OFF = 32768;

// ---------------- K0: fp32 -> f16 convert (+ zero done2) ----------------
__global__ void prep_kernel(const float4* __restrict__ X4,
                            ushort4* __restrict__ Xh4,
                            unsigned* __restrict__ done2) {
  int gid = blockIdx.x * 256 + threadIdx.x;  // grid exactly N*D/4 threads
  if (gid == 0) *done2 = 0u;
  float4 v = X4[gid];
  ushort4 o;
  o.x = __half_as_ushort(__float2half_rn(v.x));
  o.y = __half_as_ushort(__float2half_rn(v.y));
  o.z = __half_as_ushort(__float2half_rn(v.z));
  o.w = __half_as_ushort(__float2half_rn(v.w));
  Xh4[gid] = o;
}

// ---------------- K1: 128x128-tile X*X^T, dbuf, stats + in-wave top-10 ------
// 528 blocks x 512 threads (8 waves, 2M x 4N wave grid, 64x32 per wave).
// LDS ~66 KB -> 2 blocks/CU. One barrier per K-step (verified R1).
// Top-10 via register wave_sel10<32> + 80->10 block merge (R0's proven
// pattern; NO global atomics, no serial recompute).
__global__ __launch_bounds__(512, 4) void gemm_stats_kernel(
    const _Float16* __restrict__ Xh, const int* __restrict__ tgt,
    float* __restrict__ slots, float* __restrict__ top10g) {
  __shared__ _Float16 As[2][128 * 64];  // 2 x 16 KB
  __shared__ _Float16 Bs[2][128 * 64];  // 2 x 16 KB
  __shared__ int tA[128], tB[128];
  __shared__ float redf[2][8];
  __shared__ unsigned redu[8];
  __shared__ float wml[80];  // 8 waves x 10 top values

  int tid = threadIdx.x;

  // decode upper-triangle tile (br <= bc)
  int id = blockIdx.x, br = 0;
  while (id >= (NT - br)) { id -= (NT - br); br++; }
  int bc = br + id;

  if (tid < 128) tA[tid] = tgt[br * 128 + tid];
  else if (tid < 256) tB[tid - 128] = tgt[bc * 128 + (tid - 128)];

  int lane = tid & 63, wave = tid >> 6;
  int wm2 = (wave >> 2) << 6;  // 0 or 64: wave row-half
  int wn2 = (wave & 3) << 5;   // 0,32,64,96: wave col-quarter
  int lrow = lane & 15;
  int q4 = lane >> 4;
  int x7 = lrow & 7;
  int quad4 = q4 * 4;

  // staging: issue i (0..1) covers chunks C = i*512 + tid (1024 16B chunks
  // per matrix); row = C>>3, pos p = C&7 holds global chunk p^(row&7).
  int srow[2], scol[2], sdst[2];
#pragma unroll
  for (int i = 0; i < 2; i++) {
    int C = i * 512 + tid;
    int row = C >> 3, p = C & 7;
    srow[i] = row;
    scol[i] = (p ^ (row & 7)) * 8;
    sdst[i] = (i * 8 + wave) * 512;  // wave-uniform elem base (+lane*8 by HW)
  }
  const _Float16* Arow = Xh + (size_t)(br * 128) * D;
  const _Float16* Brow = Xh + (size_t)(bc * 128) * D;

  // prologue: stage k0=0 into buffer 0
#pragma unroll
  for (int i = 0; i < 2; i++) {
    load_lds16(Arow + srow[i] * D + scol[i], &As[0][sdst[i]]);
    load_lds16(Brow + srow[i] * D + scol[i], &Bs[0][sdst[i]]);
  }

  f32x4 acc[4][2] = {};
#pragma unroll
  for (int t = 0; t < 8; t++) {
    int cur = t & 1;
    __syncthreads();  // drains vmcnt: buf[cur] visible; buf[cur^1] free
    if (t < 7) {
      int k0 = (t + 1) * 64;
#pragma unroll
      for (int i = 0; i < 2; i++) {
        load_lds16(Arow + srow[i] * D + k0 + scol[i], &As[cur ^ 1][sdst[i]]);
        load_lds16(Brow + srow[i] * D + k0 + scol[i], &Bs[cur ^ 1][sdst[i]]);
      }
    }
#pragma unroll
    for (int ks = 0; ks < 64; ks += 32) {
      int c0 = ks >> 3;
      f16x8 af[4], bf[2];
#pragma unroll
      for (int mi = 0; mi < 4; mi++)
        af[mi] = *(const f16x8*)&As[cur][(wm2 + mi * 16 + lrow) * 64 +
                                         ((c0 + q4) ^ x7) * 8];
#pragma unroll
      for (int ni = 0; ni < 2; ni++)
        bf[ni] = *(const f16x8*)&Bs[cur][(wn2 + ni * 16 + lrow) * 64 +
                                         ((c0 + q4) ^ x7) * 8];
#pragma unroll
      for (int mi = 0; mi < 4; mi++)
#pragma unroll
        for (int ni = 0; ni < 2; ni++)
          acc[mi][ni] = __builtin_amdgcn_mfma_f32_16x16x32_f16(
              af[mi], bf[ni], acc[mi][ni], 0, 0, 0);
    }
  }

  // ---- epilogue: masks, hinge, stats, 32 values/thread -> wave top-10 ----
  int tj[2];
#pragma unroll
  for (int ni = 0; ni < 2; ni++) tj[ni] = tB[wn2 + ni * 16 + lrow];

  float lsv = 0.f, lsp = 0.f;
  unsigned cz = 0;  // cntp | zeros<<16 (block totals <= 16384 each)
  int ib = br * 128 + wm2 + quad4;
  int jb = bc * 128 + wn2 + lrow;

  float vals[32];
#pragma unroll
  for (int mi = 0; mi < 4; mi++) {
#pragma unroll
    for (int r = 0; r < 4; r++) {
      int trow = tA[wm2 + mi * 16 + quad4 + r];
      int i = ib + mi * 16 + r;
#pragma unroll
      for (int ni = 0; ni < 2; ni++) {
        float s = acc[mi][ni][r];
        int j = jb + ni * 16;
        bool valid = j > i;  // strict upper triangle; doubled at the end
        bool pos = valid && (trow == tj[ni]);
        float loss = fmaxf(0.5f + (pos ? -s : s), 0.0f);
        if (valid) { lsv += s; if (loss == 0.0f) cz += 0x10000u; }
        if (pos) { lsp += s; cz += 1u; }
        vals[(mi * 2 + ni) * 4 + r] = valid ? loss : SENT;
      }
    }
  }

  // stats: wave shuffle reduce
#pragma unroll
  for (int o = 32; o > 0; o >>= 1) {
    lsv += __shfl_down(lsv, o);
    lsp += __shfl_down(lsp, o);
    cz += __shfl_down(cz, o);
  }
  if (lane == 0) {
    redf[0][wave] = lsv; redf[1][wave] = lsp; redu[wave] = cz;
  }

  // top-10: per-wave register selection, publish to LDS
  float wl[10];
  wave_sel10<32>(vals, wl);
  if (lane == 0) {
#pragma unroll
    for (int r = 0; r < 10; r++) wml[wave * 10 + r] = wl[r];
  }
  __syncthreads();

  if (tid == 0) {
    float a = 0.f, b = 0.f;
    unsigned c = 0;
#pragma unroll
    for (int w = 0; w < 8; w++) { a += redf[0][w]; b += redf[1][w]; c += redu[w]; }
    slots[blockIdx.x] = a;
    slots[NBLK + blockIdx.x] = b;
    ((unsigned*)slots)[2 * NBLK + blockIdx.x] = c;
  }
  // wave 0: merge 8 lists (80 values)
  if (wave == 0) {
    float m2[2];
    m2[0] = wml[lane];  // lane < 64 < 80: always a real slot
    m2[1] = (lane + 64 < 80) ? wml[lane + 64] : SENT;
    float b10[10];
    wave_sel10<2>(m2, b10);
    if (lane == 0) {
#pragma unroll
      for (int r = 0; r < 10; r++) top10g[blockIdx.x * 10 + r] = b10[r];
    }
  }
}

// ---------------- K2: 33-block segment finalize + decoupled last-block merge
// R0's proven structure: each block reduces 16 tile-blocks (stats + top-10
// over 160), writes segment row; last-arriving block merges 33 segments.
__global__ __launch_bounds__(256) void finalize_kernel(
    const float* __restrict__ slots, const float* __restrict__ top10g,
    float* __restrict__ segL2, unsigned* __restrict__ done2,
    float* __restrict__ out) {
  const float* blk_sumv = slots;
  const float* blk_sump = slots + NBLK;
  const unsigned* blk_cnt = (const unsigned*)(slots + 2 * NBLK);
  float* ssumv = segL2;
  float* ssump = segL2 + NSEG;
  unsigned* scv = (unsigned*)(segL2 + 2 * NSEG);
  unsigned* szz = (unsigned*)(segL2 + 3 * NSEG);
  float* st10 = segL2 + 4 * NSEG;

  __shared__ float wml[40];
  __shared__ int lastFlag;

  int tid = threadIdx.x;
  int lane = tid & 63, wave = tid >> 6;
  int f = blockIdx.x;

  // segment stats: 16 tile-block rows (data on wave 0, lanes 0..15)
  float sv = 0.f, sp = 0.f;
  unsigned cv = 0, zz = 0;
  if (tid < SEGSZ) {
    int r = f * SEGSZ + tid;
    sv = blk_sumv[r]; sp = blk_sump[r];
    unsigned c = blk_cnt[r];
    cv = c & 0xffffu; zz = c >> 16;
  }
#pragma unroll
  for (int o = 8; o > 0; o >>= 1) {
    sv += __shfl_down(sv, o);
    sp += __shfl_down(sp, o);
    cv += __shfl_down(cv, o);
    zz += __shfl_down(zz, o);
  }

  // segment top-10 over 160 values
  float v1[1];
  v1[0] = (tid < SEGSZ * 10) ? top10g[f * SEGSZ * 10 + tid] : SENT;
  float wl[10];
  wave_sel10<1>(v1, wl);
  if (lane == 0) {
#pragma unroll
    for (int r = 0; r < 10; r++) wml[wave * 10 + r] = wl[r];
  }
  __syncthreads();
  if (wave == 0) {
    float m1[1];
    m1[0] = (lane < 40) ? wml[lane] : SENT;
    float s10[10];
    wave_sel10<1>(m1, s10);
    if (lane == 0) {
      ssumv[f] = sv; ssump[f] = sp; scv[f] = cv; szz[f] = zz;
#pragma unroll
      for (int r = 0; r < 10; r++) st10[f * 10 + r] = s10[r];
    }
  }
  __syncthreads();

  // decoupled final merge by the last-arriving block
  if (tid == 0) {
    __threadfence();
    unsigned old = atomicAdd(done2, 1u);
    lastFlag = (old == NSEG - 1);
  }
  __syncthreads();
  if (!lastFlag) return;
  __threadfence();

  // final stats over 33 segment rows (data on wave 0, lanes 0..32)
  float sv2 = 0.f, sp2 = 0.f;
  unsigned cv2 = 0, zz2 = 0;
  if (tid < NSEG) {
    sv2 = ssumv[tid]; sp2 = ssump[tid];
    cv2 = scv[tid]; zz2 = szz[tid];
  }
#pragma unroll
  for (int o = 32; o > 0; o >>= 1) {
    sv2 += __shfl_down(sv2, o);
    sp2 += __shfl_down(sp2, o);
    cv2 += __shfl_down(cv2, o);
    zz2 += __shfl_down(zz2, o);
  }

  // final top-10 over 330 floats
  float v2[2];
  v2[0] = (tid < NSEG * 10) ? st10[tid] : SENT;
  int g2 = tid + 256;
  v2[1] = (g2 < NSEG * 10) ? st10[g2] : SENT;
  float wl2[10];
  wave_sel10<2>(v2, wl2);
  if (lane == 0) {
#pragma unroll
    for (int r = 0; r < 10; r++) wml[wave * 10 + r] = wl2[r];
  }
  __syncthreads();

  if (wave == 0) {
    float m1[1];
    m1[0] = (lane < 40) ? wml[lane] : SENT;
    float f10[10];
    wave_sel10<1>(m1, f10);
    if (lane == 0) {
      float topsum = 0.f;
#pragma unroll
      for (int r = 0; r < 10; r++) topsum += f10[r];
      // full-matrix multiset = upper-triangle doubled: top-20 mean == top-10
      // mean; counts double in numerator and denominator (cancel in means)
      out[0] = topsum * 0.1f;
      out[1] = (float)(2u * zz2);
      out[2] = sp2 / (float)cv2;
      out[3] = (sv2 - sp2) / (float)(TCV - cv2);
    }
  }
}

extern "C" void kernel_launch(void* const* d_in, const int* in_sizes, int n_in,
                              void* d_out, int out_size, void* d_ws,
                              size_t ws_size, hipStream_t stream) {
  const float* X = (const float*)d_in[0];
  const int* tgt = (const int*)d_in[1];
  float* out = (float*)d_out;
  char* ws = (char*)d_ws;

  float* slots = (float*)ws;
  float* top10g = slots + TOP10G_IDX;
  unsigned* done2 = (unsigned*)(slots + DONE2_IDX);
  float* segL2 = slots + SEGL2_IDX;
  _Float16* Xh = (_Float16*)(ws + XH_OFF);

  prep_kernel<<<(N * D / 4) / 256, 256, 0, stream>>>((const float4*)X,
                                                     (ushort4*)Xh, done2);
  gemm_stats_kernel<<<NBLK, 512, 0, stream>>>(Xh, tgt, slots, top10g);
  finalize_kernel<<<NSEG, 256, 0, stream>>>(slots, top10g, segL2, done2, out);
}

// Round 4
// 113.421 us; speedup vs baseline: 1.3135x; 1.0101x over previous
//
#include <hip/hip_runtime.h>
#include <hip/hip_fp16.h>

// Problem constants (fixed by the reference setup)
constexpr int N = 4096;
constexpr int D = 512;
constexpr int NT = 32;                   // 4096 / 128 tile-rows
constexpr int NBLK = NT * (NT + 1) / 2;  // 528 upper-triangle tiles
constexpr float SENT = -1e30f;           // sentinel (invalid sites / empty slots)
constexpr unsigned TCV = 8386560u;       // N*(N-1)/2 valid strict-upper pairs

// Per-block candidate prefilter threshold. sims ~ N(0, 1/512); loss >= 0.63
// <=> |s| >= 2.94 sigma => ~27 candidates per 128x128 block (Poisson).
// Exactness NEVER depends on T0: blocks with cnt<10 or cnt>CCAP take the
// exact full-selection fallback, so every block always emits its exact top-10.
constexpr float T0 = 0.63f;
constexpr unsigned CCAP = 256;

typedef _Float16 f16x8 __attribute__((ext_vector_type(8)));
typedef float f32x4 __attribute__((ext_vector_type(4)));

// async 16B/lane global->LDS (wave-uniform LDS base + lane*16)
__device__ __forceinline__ void load_lds16(const _Float16* g, _Float16* l) {
  __builtin_amdgcn_global_load_lds(
      (const __attribute__((address_space(1))) void*)g,
      (__attribute__((address_space(3))) void*)l, 16, 0, 0);
}

// Exact wave top-10 by repeated selection over per-lane register candidates.
// out[r] ends up wave-uniform. Duplicates preserved (leader pops ONE copy).
// NOTE: mutates vals[] on leader lanes.
template <int M>
__device__ __forceinline__ void wave_sel10(float (&vals)[M], float (&out)[10]) {
  int lane = threadIdx.x & 63;
  float lm = vals[0];
#pragma unroll
  for (int k = 1; k < M; k++) lm = fmaxf(lm, vals[k]);
#pragma unroll
  for (int r = 0; r < 10; r++) {
    float wmx = lm;
#pragma unroll
    for (int ofs = 1; ofs < 64; ofs <<= 1)
      wmx = fmaxf(wmx, __shfl_xor(wmx, ofs));
    out[r] = wmx;
    unsigned long long b = __ballot(lm == wmx);
    int leader = __ffsll(b) - 1;
    if (lane == leader) {
      bool found = false;
#pragma unroll
      for (int k = 0; k < M; k++) {
        bool hit = !found && (vals[k] == wmx);
        vals[k] = hit ? SENT : vals[k];
        found = found || hit;
      }
      lm = vals[0];
#pragma unroll
      for (int k = 1; k < M; k++) lm = fmaxf(lm, vals[k]);
    }
  }
}

// ws layout (float indices unless noted):
//   [0, 528)       f32 blk_sumv
//   [528, 1056)    f32 blk_sump
//   [1056, 1584)   u32 cntpack  (cntp | zeros<<16; per-block totals <= 16384)
//   [1584, 6864)   f32 top10g[528*10]
//   6864           u32 done2 (zeroed by prep)
//   byte 32768:    f16 Xh[N*D]
constexpr int TOP10G_IDX = 1584;
constexpr int DONE2_IDX = 6864;
constexpr int XH_OFF = 32768;

// ---------------- K0: fp32 -> f16 convert (+ zero done2) ----------------
__global__ void prep_kernel(const float4* __restrict__ X4,
                            ushort4* __restrict__ Xh4,
                            unsigned* __restrict__ done2) {
  int gid = blockIdx.x * 256 + threadIdx.x;  // grid exactly N*D/4 threads
  if (gid == 0) *done2 = 0u;
  float4 v = X4[gid];
  ushort4 o;
  o.x = __half_as_ushort(__float2half_rn(v.x));
  o.y = __half_as_ushort(__float2half_rn(v.y));
  o.z = __half_as_ushort(__float2half_rn(v.z));
  o.w = __half_as_ushort(__float2half_rn(v.w));
  Xh4[gid] = o;
}

// ---------------- K1: 128x128-tile X*X^T + stats + prefiltered top-10 ------
// 528 blocks x 512 threads (8 waves, 2M x 4N wave grid, 64x32 per wave).
// LDS ~67 KB -> 2 blocks/CU. GEMM core is the verified R1 structure.
// Top-10: LDS-atomic threshold prefilter (expected ~27 pushes/block) + wave-0
// selection; exact-fallback per block; last-arriving block does the global
// merge (R0/R3's proven fence+atomic pattern), so there is NO finalize kernel.
__global__ __launch_bounds__(512, 4) void gemm_stats_kernel(
    const _Float16* __restrict__ Xh, const int* __restrict__ tgt,
    float* __restrict__ slots, float* __restrict__ top10g,
    unsigned* __restrict__ done2, float* __restrict__ out) {
  __shared__ _Float16 As[2][128 * 64];  // 2 x 16 KB
  __shared__ _Float16 Bs[2][128 * 64];  // 2 x 16 KB
  __shared__ int tA[128], tB[128];
  __shared__ float redf[2][8];
  __shared__ unsigned redu[2][8];
  __shared__ float wml[80];  // 8 waves x 10 top values
  __shared__ float cbuf[CCAP];
  __shared__ unsigned ccnt;
  __shared__ int lastFlag;

  int tid = threadIdx.x;
  if (tid == 0) ccnt = 0u;  // visible after first K-loop barrier

  // decode upper-triangle tile (br <= bc)
  int id = blockIdx.x, br = 0;
  while (id >= (NT - br)) { id -= (NT - br); br++; }
  int bc = br + id;

  if (tid < 128) tA[tid] = tgt[br * 128 + tid];
  else if (tid < 256) tB[tid - 128] = tgt[bc * 128 + (tid - 128)];

  int lane = tid & 63, wave = tid >> 6;
  int wm2 = (wave >> 2) << 6;  // 0 or 64: wave row-half
  int wn2 = (wave & 3) << 5;   // 0,32,64,96: wave col-quarter
  int lrow = lane & 15;
  int q4 = lane >> 4;
  int x7 = lrow & 7;
  int quad4 = q4 * 4;

  // staging: issue i (0..1) covers chunks C = i*512 + tid (1024 16B chunks
  // per matrix); row = C>>3, pos p = C&7 holds global chunk p^(row&7).
  int srow[2], scol[2], sdst[2];
#pragma unroll
  for (int i = 0; i < 2; i++) {
    int C = i * 512 + tid;
    int row = C >> 3, p = C & 7;
    srow[i] = row;
    scol[i] = (p ^ (row & 7)) * 8;
    sdst[i] = (i * 8 + wave) * 512;  // wave-uniform elem base (+lane*8 by HW)
  }
  const _Float16* Arow = Xh + (size_t)(br * 128) * D;
  const _Float16* Brow = Xh + (size_t)(bc * 128) * D;

  // prologue: stage k0=0 into buffer 0
#pragma unroll
  for (int i = 0; i < 2; i++) {
    load_lds16(Arow + srow[i] * D + scol[i], &As[0][sdst[i]]);
    load_lds16(Brow + srow[i] * D + scol[i], &Bs[0][sdst[i]]);
  }

  f32x4 acc[4][2] = {};
#pragma unroll
  for (int t = 0; t < 8; t++) {
    int cur = t & 1;
    __syncthreads();  // drains vmcnt: buf[cur] visible; buf[cur^1] free
    if (t < 7) {
      int k0 = (t + 1) * 64;
#pragma unroll
      for (int i = 0; i < 2; i++) {
        load_lds16(Arow + srow[i] * D + k0 + scol[i], &As[cur ^ 1][sdst[i]]);
        load_lds16(Brow + srow[i] * D + k0 + scol[i], &Bs[cur ^ 1][sdst[i]]);
      }
    }
#pragma unroll
    for (int ks = 0; ks < 64; ks += 32) {
      int c0 = ks >> 3;
      f16x8 af[4], bf[2];
#pragma unroll
      for (int mi = 0; mi < 4; mi++)
        af[mi] = *(const f16x8*)&As[cur][(wm2 + mi * 16 + lrow) * 64 +
                                         ((c0 + q4) ^ x7) * 8];
#pragma unroll
      for (int ni = 0; ni < 2; ni++)
        bf[ni] = *(const f16x8*)&Bs[cur][(wn2 + ni * 16 + lrow) * 64 +
                                         ((c0 + q4) ^ x7) * 8];
#pragma unroll
      for (int mi = 0; mi < 4; mi++)
#pragma unroll
        for (int ni = 0; ni < 2; ni++)
          acc[mi][ni] = __builtin_amdgcn_mfma_f32_16x16x32_f16(
              af[mi], bf[ni], acc[mi][ni], 0, 0, 0);
    }
  }

  // ---- epilogue: stats + LDS-atomic candidate prefilter (loss inline) ----
  int tj[2];
#pragma unroll
  for (int ni = 0; ni < 2; ni++) tj[ni] = tB[wn2 + ni * 16 + lrow];

  float lsv = 0.f, lsp = 0.f;
  unsigned cz = 0;  // cntp | zeros<<16 (block totals <= 16384 each)
  int ib = br * 128 + wm2 + quad4;
  int jb = bc * 128 + wn2 + lrow;
#pragma unroll
  for (int mi = 0; mi < 4; mi++) {
#pragma unroll
    for (int r = 0; r < 4; r++) {
      int trow = tA[wm2 + mi * 16 + quad4 + r];
      int i = ib + mi * 16 + r;
#pragma unroll
      for (int ni = 0; ni < 2; ni++) {
        float s = acc[mi][ni][r];
        int j = jb + ni * 16;
        bool valid = j > i;  // strict upper triangle; doubled at the end
        bool pos = valid && (trow == tj[ni]);
        float loss = fmaxf(0.5f + (pos ? -s : s), 0.0f);
        if (valid) {
          lsv += s;
          if (loss == 0.0f) cz += 0x10000u;
          if (loss >= T0) {  // rare (~27/block): LDS atomic push
            unsigned p = atomicAdd(&ccnt, 1u);
            if (p < CCAP) cbuf[p] = loss;
          }
        }
        if (pos) { lsp += s; cz += 1u; }
      }
    }
  }
#pragma unroll
  for (int o = 32; o > 0; o >>= 1) {
    lsv += __shfl_down(lsv, o);
    lsp += __shfl_down(lsp, o);
    cz += __shfl_down(cz, o);
  }
  if (lane == 0) {
    redf[0][wave] = lsv; redf[1][wave] = lsp; redu[0][wave] = cz;
  }
  __syncthreads();  // ccnt final; redf/redu visible

  unsigned cc = ccnt;  // block-uniform
  if (cc >= 10u && cc <= CCAP) {
    // fast path: block top-10 == top-10 of candidates (>=10 values >= T0
    // exist, so the block's 10 largest are all >= T0 and all captured)
    if (wave == 0) {
      float m4[4];
#pragma unroll
      for (int k = 0; k < 4; k++) {
        unsigned g = lane + k * 64u;
        m4[k] = (g < cc) ? cbuf[g] : SENT;
      }
      float b10[10];
      wave_sel10<4>(m4, b10);
      if (lane == 0) {
#pragma unroll
        for (int r = 0; r < 10; r++) top10g[blockIdx.x * 10 + r] = b10[r];
      }
    }
  } else {
    // exact fallback (rare): rebuild per-thread losses, full selection
    float vals[32];
#pragma unroll
    for (int mi = 0; mi < 4; mi++) {
#pragma unroll
      for (int r = 0; r < 4; r++) {
        int trow = tA[wm2 + mi * 16 + quad4 + r];
        int i = ib + mi * 16 + r;
#pragma unroll
        for (int ni = 0; ni < 2; ni++) {
          float s = acc[mi][ni][r];
          int j = jb + ni * 16;
          bool valid = j > i;
          bool pos = valid && (trow == tj[ni]);
          float loss = fmaxf(0.5f + (pos ? -s : s), 0.0f);
          vals[(mi * 2 + ni) * 4 + r] = valid ? loss : SENT;
        }
      }
    }
    float wl[10];
    wave_sel10<32>(vals, wl);
    if (lane == 0) {
#pragma unroll
      for (int r = 0; r < 10; r++) wml[wave * 10 + r] = wl[r];
    }
    __syncthreads();
    if (wave == 0) {
      float m2[2];
      m2[0] = wml[lane];
      m2[1] = (lane + 64 < 80) ? wml[lane + 64] : SENT;
      float b10[10];
      wave_sel10<2>(m2, b10);
      if (lane == 0) {
#pragma unroll
        for (int r = 0; r < 10; r++) top10g[blockIdx.x * 10 + r] = b10[r];
      }
    }
  }
  if (tid == 0) {
    float a = 0.f, b = 0.f;
    unsigned c = 0;
#pragma unroll
    for (int w = 0; w < 8; w++) {
      a += redf[0][w]; b += redf[1][w]; c += redu[0][w];
    }
    slots[blockIdx.x] = a;
    slots[NBLK + blockIdx.x] = b;
    ((unsigned*)slots)[2 * NBLK + blockIdx.x] = c;
  }
  __syncthreads();  // all block results issued (waves drain vmcnt at barrier)

  // ---- decoupled last-block global merge (R0/R3's proven pattern) ----
  if (tid == 0) {
    __threadfence();
    unsigned old = atomicAdd(done2, 1u);
    lastFlag = (old == NBLK - 1);
  }
  __syncthreads();
  if (!lastFlag) return;
  __threadfence();

  // stats over 528 block rows
  float sv = 0.f, sp = 0.f;
  unsigned cv = 0, zz = 0;
#pragma unroll
  for (int k = 0; k < 2; k++) {
    int r = tid + k * 512;
    if (r < NBLK) {
      sv += slots[r];
      sp += slots[NBLK + r];
      unsigned c = ((const unsigned*)slots)[2 * NBLK + r];
      cv += c & 0xffffu;
      zz += c >> 16;
    }
  }
#pragma unroll
  for (int o = 32; o > 0; o >>= 1) {
    sv += __shfl_down(sv, o);
    sp += __shfl_down(sp, o);
    cv += __shfl_down(cv, o);
    zz += __shfl_down(zz, o);
  }
  if (lane == 0) {
    redf[0][wave] = sv; redf[1][wave] = sp;
    redu[0][wave] = cv; redu[1][wave] = zz;
  }

  // top-10 over 5280 floats (8 waves x 704-value slices, then 80 -> 10)
  float v11[11];
#pragma unroll
  for (int k = 0; k < 11; k++) {
    int g = tid + k * 512;
    v11[k] = (g < NBLK * 10) ? top10g[g] : SENT;
  }
  float wl2[10];
  wave_sel10<11>(v11, wl2);
  if (lane == 0) {
#pragma unroll
    for (int r = 0; r < 10; r++) wml[wave * 10 + r] = wl2[r];
  }
  __syncthreads();

  if (wave == 0) {
    float m2[2];
    m2[0] = wml[lane];
    m2[1] = (lane + 64 < 80) ? wml[lane + 64] : SENT;
    float f10[10];
    wave_sel10<2>(m2, f10);
    if (lane == 0) {
      float topsum = 0.f;
#pragma unroll
      for (int r = 0; r < 10; r++) topsum += f10[r];
      float tsv = 0.f, tsp = 0.f;
      unsigned tcv = 0, tzz = 0;
#pragma unroll
      for (int w = 0; w < 8; w++) {
        tsv += redf[0][w]; tsp += redf[1][w];
        tcv += redu[0][w]; tzz += redu[1][w];
      }
      // full-matrix multiset = upper-triangle doubled: top-20 mean == top-10
      // mean; counts double in numerator and denominator (cancel in means)
      out[0] = topsum * 0.1f;
      out[1] = (float)(2u * tzz);
      out[2] = tsp / (float)tcv;
      out[3] = (tsv - tsp) / (float)(TCV - tcv);
    }
  }
}

extern "C" void kernel_launch(void* const* d_in, const int* in_sizes, int n_in,
                              void* d_out, int out_size, void* d_ws,
                              size_t ws_size, hipStream_t stream) {
  const float* X = (const float*)d_in[0];
  const int* tgt = (const int*)d_in[1];
  float* out = (float*)d_out;
  char* ws = (char*)d_ws;

  float* slots = (float*)ws;
  float* top10g = slots + TOP10G_IDX;
  unsigned* done2 = (unsigned*)(slots + DONE2_IDX);
  _Float16* Xh = (_Float16*)(ws + XH_OFF);

  prep_kernel<<<(N * D / 4) / 256, 256, 0, stream>>>((const float4*)X,
                                                     (ushort4*)Xh, done2);
  gemm_stats_kernel<<<NBLK, 512, 0, stream>>>(Xh, tgt, slots, top10g, done2,
                                              out);
}

// Round 5
// 103.623 us; speedup vs baseline: 1.4377x; 1.0945x over previous
//
#include <hip/hip_runtime.h>
#include <hip/hip_fp16.h>

// Problem constants (fixed by the reference setup)
constexpr int N = 4096;
constexpr int D = 512;
constexpr int NT = 32;                   // 4096 / 128 tile-rows
constexpr int NBLK = NT * (NT + 1) / 2;  // 528 upper-triangle tiles
constexpr float SENT = -1e30f;           // sentinel (invalid sites / empty slots)
constexpr unsigned TCV = 8386560u;       // N*(N-1)/2 valid strict-upper pairs

// Per-block candidate prefilter threshold. sims ~ N(0, 1/512); loss >= 0.63
// <=> |s| >= 2.94 sigma => ~27 candidates per 128x128 block (Poisson).
// Exactness NEVER depends on T0: blocks with cnt<10 or cnt>CCAP take the
// exact full-selection fallback, so every block always emits its exact top-10.
constexpr float T0 = 0.63f;
constexpr unsigned CCAP = 256;

typedef _Float16 f16x8 __attribute__((ext_vector_type(8)));
typedef float f32x4 __attribute__((ext_vector_type(4)));

// async 16B/lane global->LDS (wave-uniform LDS base + lane*16)
__device__ __forceinline__ void load_lds16(const _Float16* g, _Float16* l) {
  __builtin_amdgcn_global_load_lds(
      (const __attribute__((address_space(1))) void*)g,
      (__attribute__((address_space(3))) void*)l, 16, 0, 0);
}

// Exact wave top-10 by repeated selection over per-lane register candidates.
// out[r] ends up wave-uniform. Duplicates preserved (leader pops ONE copy).
// NOTE: mutates vals[] on leader lanes.
template <int M>
__device__ __forceinline__ void wave_sel10(float (&vals)[M], float (&out)[10]) {
  int lane = threadIdx.x & 63;
  float lm = vals[0];
#pragma unroll
  for (int k = 1; k < M; k++) lm = fmaxf(lm, vals[k]);
#pragma unroll
  for (int r = 0; r < 10; r++) {
    float wmx = lm;
#pragma unroll
    for (int ofs = 1; ofs < 64; ofs <<= 1)
      wmx = fmaxf(wmx, __shfl_xor(wmx, ofs));
    out[r] = wmx;
    unsigned long long b = __ballot(lm == wmx);
    int leader = __ffsll(b) - 1;
    if (lane == leader) {
      bool found = false;
#pragma unroll
      for (int k = 0; k < M; k++) {
        bool hit = !found && (vals[k] == wmx);
        vals[k] = hit ? SENT : vals[k];
        found = found || hit;
      }
      lm = vals[0];
#pragma unroll
      for (int k = 1; k < M; k++) lm = fmaxf(lm, vals[k]);
    }
  }
}

// ws layout (float indices unless noted):
//   [0, 528)       f32 blk_sumv
//   [528, 1056)    f32 blk_sump
//   [1056, 1584)   u32 cntpack  (cntp | zeros<<16; per-block totals <= 16384)
//   [1584, 6864)   f32 top10g[528*10]
//   byte 32768:    f16 Xh[N*D]
constexpr int TOP10G_IDX = 1584;
constexpr int XH_OFF = 32768;

// ---------------- K0: fp32 -> f16 convert ----------------
__global__ void prep_kernel(const float4* __restrict__ X4,
                            ushort4* __restrict__ Xh4) {
  int gid = blockIdx.x * 256 + threadIdx.x;  // grid exactly N*D/4 threads
  float4 v = X4[gid];
  ushort4 o;
  o.x = __half_as_ushort(__float2half_rn(v.x));
  o.y = __half_as_ushort(__float2half_rn(v.y));
  o.z = __half_as_ushort(__float2half_rn(v.z));
  o.w = __half_as_ushort(__float2half_rn(v.w));
  Xh4[gid] = o;
}

// ---------------- K1: 128x128-tile X*X^T + stats + prefiltered top-10 ------
// 528 blocks x 512 threads (8 waves, 2M x 4N wave grid, 64x32 per wave).
// LDS ~67 KB -> 2 blocks/CU. GEMM core is the verified R1 structure.
// Top-10: LDS-atomic threshold prefilter (~27 pushes/block expected) + wave-0
// selection over the candidate buffer; exact full-selection fallback per
// block when the prefilter can't prove exactness. NO global atomics, NO
// fence/fused merge (R4 showed those cost 25-35 us).
__global__ __launch_bounds__(512, 4) void gemm_stats_kernel(
    const _Float16* __restrict__ Xh, const int* __restrict__ tgt,
    float* __restrict__ slots, float* __restrict__ top10g) {
  __shared__ _Float16 As[2][128 * 64];  // 2 x 16 KB
  __shared__ _Float16 Bs[2][128 * 64];  // 2 x 16 KB
  __shared__ int tA[128], tB[128];
  __shared__ float redf[2][8];
  __shared__ unsigned redu[8];
  __shared__ float wml[80];  // 8 waves x 10 top values (fallback)
  __shared__ float cbuf[CCAP];
  __shared__ unsigned ccnt;

  int tid = threadIdx.x;
  if (tid == 0) ccnt = 0u;  // visible after first K-loop barrier

  // decode upper-triangle tile (br <= bc)
  int id = blockIdx.x, br = 0;
  while (id >= (NT - br)) { id -= (NT - br); br++; }
  int bc = br + id;

  if (tid < 128) tA[tid] = tgt[br * 128 + tid];
  else if (tid < 256) tB[tid - 128] = tgt[bc * 128 + (tid - 128)];

  int lane = tid & 63, wave = tid >> 6;
  int wm2 = (wave >> 2) << 6;  // 0 or 64: wave row-half
  int wn2 = (wave & 3) << 5;   // 0,32,64,96: wave col-quarter
  int lrow = lane & 15;
  int q4 = lane >> 4;
  int x7 = lrow & 7;
  int quad4 = q4 * 4;

  // staging: issue i (0..1) covers chunks C = i*512 + tid (1024 16B chunks
  // per matrix); row = C>>3, pos p = C&7 holds global chunk p^(row&7).
  int srow[2], scol[2], sdst[2];
#pragma unroll
  for (int i = 0; i < 2; i++) {
    int C = i * 512 + tid;
    int row = C >> 3, p = C & 7;
    srow[i] = row;
    scol[i] = (p ^ (row & 7)) * 8;
    sdst[i] = (i * 8 + wave) * 512;  // wave-uniform elem base (+lane*8 by HW)
  }
  const _Float16* Arow = Xh + (size_t)(br * 128) * D;
  const _Float16* Brow = Xh + (size_t)(bc * 128) * D;

  // prologue: stage k0=0 into buffer 0
#pragma unroll
  for (int i = 0; i < 2; i++) {
    load_lds16(Arow + srow[i] * D + scol[i], &As[0][sdst[i]]);
    load_lds16(Brow + srow[i] * D + scol[i], &Bs[0][sdst[i]]);
  }

  f32x4 acc[4][2] = {};
#pragma unroll
  for (int t = 0; t < 8; t++) {
    int cur = t & 1;
    __syncthreads();  // drains vmcnt: buf[cur] visible; buf[cur^1] free
    if (t < 7) {
      int k0 = (t + 1) * 64;
#pragma unroll
      for (int i = 0; i < 2; i++) {
        load_lds16(Arow + srow[i] * D + k0 + scol[i], &As[cur ^ 1][sdst[i]]);
        load_lds16(Brow + srow[i] * D + k0 + scol[i], &Bs[cur ^ 1][sdst[i]]);
      }
    }
#pragma unroll
    for (int ks = 0; ks < 64; ks += 32) {
      int c0 = ks >> 3;
      f16x8 af[4], bf[2];
#pragma unroll
      for (int mi = 0; mi < 4; mi++)
        af[mi] = *(const f16x8*)&As[cur][(wm2 + mi * 16 + lrow) * 64 +
                                         ((c0 + q4) ^ x7) * 8];
#pragma unroll
      for (int ni = 0; ni < 2; ni++)
        bf[ni] = *(const f16x8*)&Bs[cur][(wn2 + ni * 16 + lrow) * 64 +
                                         ((c0 + q4) ^ x7) * 8];
#pragma unroll
      for (int mi = 0; mi < 4; mi++)
#pragma unroll
        for (int ni = 0; ni < 2; ni++)
          acc[mi][ni] = __builtin_amdgcn_mfma_f32_16x16x32_f16(
              af[mi], bf[ni], acc[mi][ni], 0, 0, 0);
    }
  }

  // ---- epilogue: stats + LDS-atomic candidate prefilter (loss inline) ----
  int tj[2];
#pragma unroll
  for (int ni = 0; ni < 2; ni++) tj[ni] = tB[wn2 + ni * 16 + lrow];

  float lsv = 0.f, lsp = 0.f;
  unsigned cz = 0;  // cntp | zeros<<16 (block totals <= 16384 each)
  int ib = br * 128 + wm2 + quad4;
  int jb = bc * 128 + wn2 + lrow;
#pragma unroll
  for (int mi = 0; mi < 4; mi++) {
#pragma unroll
    for (int r = 0; r < 4; r++) {
      int trow = tA[wm2 + mi * 16 + quad4 + r];
      int i = ib + mi * 16 + r;
#pragma unroll
      for (int ni = 0; ni < 2; ni++) {
        float s = acc[mi][ni][r];
        int j = jb + ni * 16;
        bool valid = j > i;  // strict upper triangle; doubled at the end
        bool pos = valid && (trow == tj[ni]);
        float loss = fmaxf(0.5f + (pos ? -s : s), 0.0f);
        if (valid) {
          lsv += s;
          if (loss == 0.0f) cz += 0x10000u;
          if (loss >= T0) {  // rare (~27/block): LDS atomic push
            unsigned p = atomicAdd(&ccnt, 1u);
            if (p < CCAP) cbuf[p] = loss;
          }
        }
        if (pos) { lsp += s; cz += 1u; }
      }
    }
  }
#pragma unroll
  for (int o = 32; o > 0; o >>= 1) {
    lsv += __shfl_down(lsv, o);
    lsp += __shfl_down(lsp, o);
    cz += __shfl_down(cz, o);
  }
  if (lane == 0) {
    redf[0][wave] = lsv; redf[1][wave] = lsp; redu[wave] = cz;
  }
  __syncthreads();  // ccnt final; redf/redu visible

  // stats store (wave 7, lane 56 is idle in the fast path -> overlaps wave 0)
  if (tid == 504) {
    float a = 0.f, b = 0.f;
    unsigned c = 0;
#pragma unroll
    for (int w = 0; w < 8; w++) { a += redf[0][w]; b += redf[1][w]; c += redu[w]; }
    slots[blockIdx.x] = a;
    slots[NBLK + blockIdx.x] = b;
    ((unsigned*)slots)[2 * NBLK + blockIdx.x] = c;
  }

  unsigned cc = ccnt;  // block-uniform
  if (cc >= 10u && cc <= CCAP) {
    // fast path: block top-10 == top-10 of candidates (>=10 values >= T0
    // exist, so the block's 10 largest are all >= T0 and all captured)
    if (wave == 0) {
      float m4[4];
#pragma unroll
      for (int k = 0; k < 4; k++) {
        unsigned g = lane + k * 64u;
        m4[k] = (g < cc) ? cbuf[g] : SENT;
      }
      float b10[10];
      wave_sel10<4>(m4, b10);
      if (lane == 0) {
#pragma unroll
        for (int r = 0; r < 10; r++) top10g[blockIdx.x * 10 + r] = b10[r];
      }
    }
  } else {
    // exact fallback (rare): rebuild per-thread losses, full selection
    float vals[32];
#pragma unroll
    for (int mi = 0; mi < 4; mi++) {
#pragma unroll
      for (int r = 0; r < 4; r++) {
        int trow = tA[wm2 + mi * 16 + quad4 + r];
        int i = ib + mi * 16 + r;
#pragma unroll
        for (int ni = 0; ni < 2; ni++) {
          float s = acc[mi][ni][r];
          int j = jb + ni * 16;
          bool valid = j > i;
          bool pos = valid && (trow == tj[ni]);
          float loss = fmaxf(0.5f + (pos ? -s : s), 0.0f);
          vals[(mi * 2 + ni) * 4 + r] = valid ? loss : SENT;
        }
      }
    }
    float wl[10];
    wave_sel10<32>(vals, wl);
    if (lane == 0) {
#pragma unroll
      for (int r = 0; r < 10; r++) wml[wave * 10 + r] = wl[r];
    }
    __syncthreads();
    if (wave == 0) {
      float m2[2];
      m2[0] = wml[lane];
      m2[1] = (lane + 64 < 80) ? wml[lane + 64] : SENT;
      float b10[10];
      wave_sel10<2>(m2, b10);
      if (lane == 0) {
#pragma unroll
        for (int r = 0; r < 10; r++) top10g[blockIdx.x * 10 + r] = b10[r];
      }
    }
  }
}

// ---------------- K2: ONE-block finalize (1024 threads, 16 waves) ----------
// Minimal work: 528 stat rows + 5280-float top-10 merge. No atomics, no
// recompute, no multi-stage. If this still profiles >= 15 us, the cost is
// structural dependent-kernel overhead, not the merge math.
__global__ __launch_bounds__(1024) void finalize_kernel(
    const float* __restrict__ slots, const float* __restrict__ top10g,
    float* __restrict__ out) {
  __shared__ float wml[160];
  __shared__ float redf[2][16];
  __shared__ unsigned redu[2][16];

  int tid = threadIdx.x, lane = tid & 63, wave = tid >> 6;

  // stats over 528 block rows (threads 0..527 each load one row)
  float sv = 0.f, sp = 0.f;
  unsigned cv = 0, zz = 0;
  if (tid < NBLK) {
    sv = slots[tid];
    sp = slots[NBLK + tid];
    unsigned c = ((const unsigned*)slots)[2 * NBLK + tid];
    cv = c & 0xffffu;
    zz = c >> 16;
  }

  // top-10 over 5280 floats: 16 waves x 6 regs (covers 6144 slots)
  float v6[6];
#pragma unroll
  for (int k = 0; k < 6; k++) {
    int g = tid + k * 1024;
    v6[k] = (g < NBLK * 10) ? top10g[g] : SENT;
  }

#pragma unroll
  for (int o = 32; o > 0; o >>= 1) {
    sv += __shfl_down(sv, o);
    sp += __shfl_down(sp, o);
    cv += __shfl_down(cv, o);
    zz += __shfl_down(zz, o);
  }
  if (lane == 0) {
    redf[0][wave] = sv; redf[1][wave] = sp;
    redu[0][wave] = cv; redu[1][wave] = zz;
  }

  float wl[10];
  wave_sel10<6>(v6, wl);
  if (lane == 0) {
#pragma unroll
    for (int r = 0; r < 10; r++) wml[wave * 10 + r] = wl[r];
  }
  __syncthreads();

  if (wave == 0) {
    float m3[3];
#pragma unroll
    for (int k = 0; k < 3; k++) {
      int g = lane + k * 64;
      m3[k] = (g < 160) ? wml[g] : SENT;
    }
    float f10[10];
    wave_sel10<3>(m3, f10);
    if (lane == 0) {
      float topsum = 0.f;
#pragma unroll
      for (int r = 0; r < 10; r++) topsum += f10[r];
      float tsv = 0.f, tsp = 0.f;
      unsigned tcv = 0, tzz = 0;
#pragma unroll
      for (int w = 0; w < 16; w++) {
        tsv += redf[0][w]; tsp += redf[1][w];
        tcv += redu[0][w]; tzz += redu[1][w];
      }
      // full-matrix multiset = upper-triangle doubled: top-20 mean == top-10
      // mean; counts double in numerator and denominator (cancel in means)
      out[0] = topsum * 0.1f;
      out[1] = (float)(2u * tzz);
      out[2] = tsp / (float)tcv;
      out[3] = (tsv - tsp) / (float)(TCV - tcv);
    }
  }
}

extern "C" void kernel_launch(void* const* d_in, const int* in_sizes, int n_in,
                              void* d_out, int out_size, void* d_ws,
                              size_t ws_size, hipStream_t stream) {
  const float* X = (const float*)d_in[0];
  const int* tgt = (const int*)d_in[1];
  float* out = (float*)d_out;
  char* ws = (char*)d_ws;

  float* slots = (float*)ws;
  float* top10g = slots + TOP10G_IDX;
  _Float16* Xh = (_Float16*)(ws + XH_OFF);

  prep_kernel<<<(N * D / 4) / 256, 256, 0, stream>>>((const float4*)X,
                                                     (ushort4*)Xh);
  gemm_stats_kernel<<<NBLK, 512, 0, stream>>>(Xh, tgt, slots, top10g);
  finalize_kernel<<<1, 1024, 0, stream>>>(slots, top10g, out);
}

// Round 6
// 97.539 us; speedup vs baseline: 1.5274x; 1.0624x over previous
//
#include <hip/hip_runtime.h>
#include <hip/hip_fp16.h>

// Problem constants (fixed by the reference setup)
constexpr int N = 4096;
constexpr int D = 512;
constexpr int NT = 32;                   // 4096 / 128 tile-rows
constexpr int NBLK = NT * (NT + 1) / 2;  // 528 upper-triangle tiles
constexpr float SENT = -1e30f;           // sentinel (invalid sites / empty slots)
constexpr unsigned TCV = 8386560u;       // N*(N-1)/2 valid strict-upper pairs

// Per-block candidate prefilter threshold. sims ~ N(0, 1/512); loss >= 0.60
// <=> s >= 0.10 (2.26 sigma) => ~194 candidates per full 128x128 block,
// ~97 per diagonal block. CCAP=320 is +9 sigma vs 194. Exactness NEVER
// depends on T0: blocks with cnt<10 or cnt>CCAP take the exact fallback.
constexpr float T0 = 0.60f;
constexpr unsigned CCAP = 320;

typedef _Float16 f16x8 __attribute__((ext_vector_type(8)));
typedef float f32x4 __attribute__((ext_vector_type(4)));

// async 16B/lane global->LDS (wave-uniform LDS base + lane*16)
__device__ __forceinline__ void load_lds16(const _Float16* g, _Float16* l) {
  __builtin_amdgcn_global_load_lds(
      (const __attribute__((address_space(1))) void*)g,
      (__attribute__((address_space(3))) void*)l, 16, 0, 0);
}

// Exact wave top-10 by repeated selection over per-lane register candidates.
// out[r] ends up wave-uniform. Duplicates preserved (leader pops ONE copy).
// NOTE: mutates vals[] on leader lanes.
template <int M>
__device__ __forceinline__ void wave_sel10(float (&vals)[M], float (&out)[10]) {
  int lane = threadIdx.x & 63;
  float lm = vals[0];
#pragma unroll
  for (int k = 1; k < M; k++) lm = fmaxf(lm, vals[k]);
#pragma unroll
  for (int r = 0; r < 10; r++) {
    float wmx = lm;
#pragma unroll
    for (int ofs = 1; ofs < 64; ofs <<= 1)
      wmx = fmaxf(wmx, __shfl_xor(wmx, ofs));
    out[r] = wmx;
    unsigned long long b = __ballot(lm == wmx);
    int leader = __ffsll(b) - 1;
    if (lane == leader) {
      bool found = false;
#pragma unroll
      for (int k = 0; k < M; k++) {
        bool hit = !found && (vals[k] == wmx);
        vals[k] = hit ? SENT : vals[k];
        found = found || hit;
      }
      lm = vals[0];
#pragma unroll
      for (int k = 1; k < M; k++) lm = fmaxf(lm, vals[k]);
    }
  }
}

// ws layout (float indices unless noted):
//   [0, 528)       f32 blk_sumv
//   [528, 1056)    f32 blk_sump
//   [1056, 1584)   u32 cntpack  (cntp | zeros<<16; per-block totals <= 16384)
//   [1584, 6864)   f32 top10g[528*10]
//   byte 32768:    f16 Xh[N*D]
constexpr int TOP10G_IDX = 1584;
constexpr int XH_OFF = 32768;

// ---------------- K0: fp32 -> f16 convert ----------------
__global__ void prep_kernel(const float4* __restrict__ X4,
                            ushort4* __restrict__ Xh4) {
  int gid = blockIdx.x * 256 + threadIdx.x;  // grid exactly N*D/4 threads
  float4 v = X4[gid];
  ushort4 o;
  o.x = __half_as_ushort(__float2half_rn(v.x));
  o.y = __half_as_ushort(__float2half_rn(v.y));
  o.z = __half_as_ushort(__float2half_rn(v.z));
  o.w = __half_as_ushort(__float2half_rn(v.w));
  Xh4[gid] = o;
}

// ---------------- K1: 128x128-tile X*X^T, 4 waves x 64x64, BK=32 -----------
// 528 blocks x 256 threads (4 waves, 2M x 2N wave grid, 64x64 per wave).
// Rationale (R5 post-mortem): the 8-wave 64x32 layout was LDS-read-bound
// (A-subtiles read 4x redundantly, 98 KB/block/K-step). 64x64 waves cut
// reads 33%; BK=32 drops LDS to ~35 KB -> 3 blocks/CU (launch_bounds 256,3)
// -> all 528 blocks co-resident (no 1.5x tail round).
// Swizzle (32-col tiles): LDS pos p of row r holds global chunk p^((r>>1)&3);
// slot mod 8 = 4(r&1) + p^((r>>1)&3) is bijective over r mod 8 => 16-lane
// column reads are 2-way per bank-group (free, m136). Read key (lrow>>1)&3
// is wave-invariant (all row bases are multiples of 16).
__global__ __launch_bounds__(256, 3) void gemm_stats_kernel(
    const _Float16* __restrict__ Xh, const int* __restrict__ tgt,
    float* __restrict__ slots, float* __restrict__ top10g) {
  __shared__ _Float16 As[2][128 * 32];  // 2 x 8 KB
  __shared__ _Float16 Bs[2][128 * 32];  // 2 x 8 KB
  __shared__ int tA[128], tB[128];
  __shared__ float redf[2][4];
  __shared__ unsigned redu[4];
  __shared__ float wml[40];  // fallback only
  __shared__ float cbuf[CCAP];
  __shared__ unsigned ccnt;

  int tid = threadIdx.x;
  if (tid == 0) ccnt = 0u;  // visible after first K-loop barrier

  // decode upper-triangle tile (br <= bc)
  int id = blockIdx.x, br = 0;
  while (id >= (NT - br)) { id -= (NT - br); br++; }
  int bc = br + id;

  if (tid < 128) tA[tid] = tgt[br * 128 + tid];
  else tB[tid - 128] = tgt[bc * 128 + (tid - 128)];

  int lane = tid & 63, wave = tid >> 6;
  int wm2 = (wave >> 1) << 6;  // 0 or 64: wave row-half
  int wn2 = (wave & 1) << 6;   // 0 or 64: wave col-half
  int lrow = lane & 15;
  int q4 = lane >> 4;          // k-chunk 0..3 (8 f16 each)
  int xk = (lrow >> 1) & 3;    // 32-col swizzle key
  int quad4 = q4 * 4;

  // staging: 512 16B chunks per matrix per K-step; issue i covers
  // C = i*256 + tid; row = C>>2, pos p = C&3 holds global chunk p^((row>>1)&3)
  int srow[2], scol[2], sdst[2];
#pragma unroll
  for (int i = 0; i < 2; i++) {
    int C = i * 256 + tid;
    int row = C >> 2, p = C & 3;
    srow[i] = row;
    scol[i] = (p ^ ((row >> 1) & 3)) * 8;
    sdst[i] = (i * 4 + wave) * 512;  // wave-uniform elem base (+lane*8 by HW)
  }
  const _Float16* Arow = Xh + (size_t)(br * 128) * D;
  const _Float16* Brow = Xh + (size_t)(bc * 128) * D;

  // prologue: stage k0=0 into buffer 0
#pragma unroll
  for (int i = 0; i < 2; i++) {
    load_lds16(Arow + srow[i] * D + scol[i], &As[0][sdst[i]]);
    load_lds16(Brow + srow[i] * D + scol[i], &Bs[0][sdst[i]]);
  }

  f32x4 acc[4][4] = {};
#pragma unroll
  for (int t = 0; t < 16; t++) {
    int cur = t & 1;
    __syncthreads();  // drains vmcnt: buf[cur] visible; buf[cur^1] free
    if (t < 15) {
      int k0 = (t + 1) * 32;
#pragma unroll
      for (int i = 0; i < 2; i++) {
        load_lds16(Arow + srow[i] * D + k0 + scol[i], &As[cur ^ 1][sdst[i]]);
        load_lds16(Brow + srow[i] * D + k0 + scol[i], &Bs[cur ^ 1][sdst[i]]);
      }
    }
    f16x8 af[4], bf[4];
#pragma unroll
    for (int mi = 0; mi < 4; mi++)
      af[mi] = *(const f16x8*)&As[cur][(wm2 + mi * 16 + lrow) * 32 +
                                       (q4 ^ xk) * 8];
#pragma unroll
    for (int ni = 0; ni < 4; ni++)
      bf[ni] = *(const f16x8*)&Bs[cur][(wn2 + ni * 16 + lrow) * 32 +
                                       (q4 ^ xk) * 8];
#pragma unroll
    for (int mi = 0; mi < 4; mi++)
#pragma unroll
      for (int ni = 0; ni < 4; ni++)
        acc[mi][ni] = __builtin_amdgcn_mfma_f32_16x16x32_f16(
            af[mi], bf[ni], acc[mi][ni], 0, 0, 0);
  }

  // ---- epilogue: stats + LDS-atomic candidate prefilter (loss inline) ----
  int tj[4];
#pragma unroll
  for (int ni = 0; ni < 4; ni++) tj[ni] = tB[wn2 + ni * 16 + lrow];

  float lsv = 0.f, lsp = 0.f;
  unsigned cz = 0;  // cntp | zeros<<16 (block totals <= 16384 each)
  int ib = br * 128 + wm2 + quad4;
  int jb = bc * 128 + wn2 + lrow;
#pragma unroll
  for (int mi = 0; mi < 4; mi++) {
#pragma unroll
    for (int r = 0; r < 4; r++) {
      int trow = tA[wm2 + mi * 16 + quad4 + r];
      int i = ib + mi * 16 + r;
#pragma unroll
      for (int ni = 0; ni < 4; ni++) {
        float s = acc[mi][ni][r];
        int j = jb + ni * 16;
        bool valid = j > i;  // strict upper triangle; doubled at the end
        bool pos = valid && (trow == tj[ni]);
        float loss = fmaxf(0.5f + (pos ? -s : s), 0.0f);
        if (valid) {
          lsv += s;
          if (loss == 0.0f) cz += 0x10000u;
          if (loss >= T0) {  // ~194/block: LDS atomic push
            unsigned p = atomicAdd(&ccnt, 1u);
            if (p < CCAP) cbuf[p] = loss;
          }
        }
        if (pos) { lsp += s; cz += 1u; }
      }
    }
  }
#pragma unroll
  for (int o = 32; o > 0; o >>= 1) {
    lsv += __shfl_down(lsv, o);
    lsp += __shfl_down(lsp, o);
    cz += __shfl_down(cz, o);
  }
  if (lane == 0) {
    redf[0][wave] = lsv; redf[1][wave] = lsp; redu[wave] = cz;
  }
  __syncthreads();  // ccnt final; redf/redu visible

  // stats store on wave 3 (overlaps wave 0's selection)
  if (tid == 192) {
    float a = 0.f, b = 0.f;
    unsigned c = 0;
#pragma unroll
    for (int w = 0; w < 4; w++) { a += redf[0][w]; b += redf[1][w]; c += redu[w]; }
    slots[blockIdx.x] = a;
    slots[NBLK + blockIdx.x] = b;
    ((unsigned*)slots)[2 * NBLK + blockIdx.x] = c;
  }

  unsigned cc = ccnt;  // block-uniform
  if (cc >= 10u && cc <= CCAP) {
    // fast path (always, statistically): block top-10 == top-10 of candidates
    if (wave == 0) {
      float m5[5];
#pragma unroll
      for (int k = 0; k < 5; k++) {
        unsigned g = lane + k * 64u;
        m5[k] = (g < cc) ? cbuf[g] : SENT;
      }
      float b10[10];
      wave_sel10<5>(m5, b10);
      if (lane == 0) {
#pragma unroll
        for (int r = 0; r < 10; r++) top10g[blockIdx.x * 10 + r] = b10[r];
      }
    }
  } else {
    // exact fallback (safety net; ~never taken at T0=0.60): rebuild losses,
    // per-wave selection over 64 regs (scratch OK here), 40 -> 10 merge
    float vals[64];
#pragma unroll
    for (int mi = 0; mi < 4; mi++) {
#pragma unroll
      for (int r = 0; r < 4; r++) {
        int trow = tA[wm2 + mi * 16 + quad4 + r];
        int i = ib + mi * 16 + r;
#pragma unroll
        for (int ni = 0; ni < 4; ni++) {
          float s = acc[mi][ni][r];
          int j = jb + ni * 16;
          bool valid = j > i;
          bool pos = valid && (trow == tj[ni]);
          float loss = fmaxf(0.5f + (pos ? -s : s), 0.0f);
          vals[(mi * 4 + ni) * 4 + r] = valid ? loss : SENT;
        }
      }
    }
    float wl[10];
    wave_sel10<64>(vals, wl);
    if (lane == 0) {
#pragma unroll
      for (int r = 0; r < 10; r++) wml[wave * 10 + r] = wl[r];
    }
    __syncthreads();
    if (wave == 0) {
      float m1[1];
      m1[0] = (lane < 40) ? wml[lane] : SENT;
      float b10[10];
      wave_sel10<1>(m1, b10);
      if (lane == 0) {
#pragma unroll
        for (int r = 0; r < 10; r++) top10g[blockIdx.x * 10 + r] = b10[r];
      }
    }
  }
}

// ---------------- K2: ONE-block finalize (1024 threads, 16 waves) ----------
// Unchanged from R5 (isolate the gemm change this round).
__global__ __launch_bounds__(1024) void finalize_kernel(
    const float* __restrict__ slots, const float* __restrict__ top10g,
    float* __restrict__ out) {
  __shared__ float wml[160];
  __shared__ float redf[2][16];
  __shared__ unsigned redu[2][16];

  int tid = threadIdx.x, lane = tid & 63, wave = tid >> 6;

  // stats over 528 block rows (threads 0..527 each load one row)
  float sv = 0.f, sp = 0.f;
  unsigned cv = 0, zz = 0;
  if (tid < NBLK) {
    sv = slots[tid];
    sp = slots[NBLK + tid];
    unsigned c = ((const unsigned*)slots)[2 * NBLK + tid];
    cv = c & 0xffffu;
    zz = c >> 16;
  }

  // top-10 over 5280 floats: 16 waves x 6 regs (covers 6144 slots)
  float v6[6];
#pragma unroll
  for (int k = 0; k < 6; k++) {
    int g = tid + k * 1024;
    v6[k] = (g < NBLK * 10) ? top10g[g] : SENT;
  }

#pragma unroll
  for (int o = 32; o > 0; o >>= 1) {
    sv += __shfl_down(sv, o);
    sp += __shfl_down(sp, o);
    cv += __shfl_down(cv, o);
    zz += __shfl_down(zz, o);
  }
  if (lane == 0) {
    redf[0][wave] = sv; redf[1][wave] = sp;
    redu[0][wave] = cv; redu[1][wave] = zz;
  }

  float wl[10];
  wave_sel10<6>(v6, wl);
  if (lane == 0) {
#pragma unroll
    for (int r = 0; r < 10; r++) wml[wave * 10 + r] = wl[r];
  }
  __syncthreads();

  if (wave == 0) {
    float m3[3];
#pragma unroll
    for (int k = 0; k < 3; k++) {
      int g = lane + k * 64;
      m3[k] = (g < 160) ? wml[g] : SENT;
    }
    float f10[10];
    wave_sel10<3>(m3, f10);
    if (lane == 0) {
      float topsum = 0.f;
#pragma unroll
      for (int r = 0; r < 10; r++) topsum += f10[r];
      float tsv = 0.f, tsp = 0.f;
      unsigned tcv = 0, tzz = 0;
#pragma unroll
      for (int w = 0; w < 16; w++) {
        tsv += redf[0][w]; tsp += redf[1][w];
        tcv += redu[0][w]; tzz += redu[1][w];
      }
      // full-matrix multiset = upper-triangle doubled: top-20 mean == top-10
      // mean; counts double in numerator and denominator (cancel in means)
      out[0] = topsum * 0.1f;
      out[1] = (float)(2u * tzz);
      out[2] = tsp / (float)tcv;
      out[3] = (tsv - tsp) / (float)(TCV - tcv);
    }
  }
}

extern "C" void kernel_launch(void* const* d_in, const int* in_sizes, int n_in,
                              void* d_out, int out_size, void* d_ws,
                              size_t ws_size, hipStream_t stream) {
  const float* X = (const float*)d_in[0];
  const int* tgt = (const int*)d_in[1];
  float* out = (float*)d_out;
  char* ws = (char*)d_ws;

  float* slots = (float*)ws;
  float* top10g = slots + TOP10G_IDX;
  _Float16* Xh = (_Float16*)(ws + XH_OFF);

  prep_kernel<<<(N * D / 4) / 256, 256, 0, stream>>>((const float4*)X,
                                                     (ushort4*)Xh);
  gemm_stats_kernel<<<NBLK, 256, 0, stream>>>(Xh, tgt, slots, top10g);
  finalize_kernel<<<1, 1024, 0, stream>>>(slots, top10g, out);
}